// Round 4
// baseline (1145.546 us; speedup 1.0000x reference)
//
#include <hip/hip_runtime.h>

// EquivariantProductBasisBlock (MACE symmetric contraction), fp32.
// B=2048, C=128, S=10, DIN=9, DOUTS=(1,3,5), PATHS=(1,3,8).
//
// R4: symmetrized table [row][mm] in LDS (219 rows x 12 floats).
//   Per (b,c): out[mm] = sum_row S[row][mm] * mono_row(x).
//   2 b's per thread (LDS broadcast rows amortized), 128 threads,
//   sched_barrier(0) per row-group to bound load hoisting (R3 spilled).
//
// mm -> (l,m): 0 -> (0,0); 1..3 -> (1,mm-1); 4..8 -> (2,mm-4); lm = l*5+m.

#define NB 2048
#define NC 128
#define NS 10

__host__ __device__ constexpr int pidx(int j, int k) {  // (j<=k) -> [0,45)
    return 9 * j - j * (j - 1) / 2 + (k - j);
}
__host__ __device__ constexpr int tidx(int i, int j, int k) {  // (i<=j<=k) -> [0,165)
    int base = 0;
    for (int a = 0; a < i; a++) base += (9 - a) * (10 - a) / 2;
    const int d = 9 - i, jj = j - i;
    return base + d * jj - jj * (jj - 1) / 2 + (k - j);
}

struct TripTab {     // i<=j<=k in lexicographic order (matches tidx)
    int ti[165], tj[165], tk[165];
    constexpr TripTab() : ti{}, tj{}, tk{} {
        int n = 0;
        for (int i = 0; i < 9; i++)
            for (int j = i; j < 9; j++)
                for (int k = j; k < 9; k++) { ti[n] = i; tj[n] = j; tk[n] = k; n++; }
    }
};
static constexpr TripTab TT{};

struct PairTab {     // j<=k in pidx order
    int pj[45], pk[45];
    constexpr PairTab() : pj{}, pk{} {
        int n = 0;
        for (int j = 0; j < 9; j++)
            for (int k = j; k < 9; k++) { pj[n] = j; pk[n] = k; n++; }
    }
};
static constexpr PairTab PT{};

// ---------------- prep: deterministic counting sort of b by species ----------
__global__ __launch_bounds__(256) void prep_kernel(const float* __restrict__ attrs,
                                                   int* __restrict__ cnt,
                                                   int* __restrict__ start,
                                                   int* __restrict__ list)
{
    __shared__ int sc_[256][NS];
    __shared__ int own_[256][NS];
    __shared__ int st_[NS];
    const int t = threadIdx.x;
    int myspec[8];
    #pragma unroll
    for (int e = 0; e < NS; e++) own_[t][e] = 0;
    #pragma unroll
    for (int r = 0; r < 8; r++) {
        const int b = t * 8 + r;
        const float* row = attrs + b * NS;
        int e = 0;
        #pragma unroll
        for (int s = 1; s < NS; s++) e = (row[s] > 0.5f) ? s : e;
        myspec[r] = e;
        own_[t][e] += 1;
    }
    #pragma unroll
    for (int e = 0; e < NS; e++) sc_[t][e] = own_[t][e];
    __syncthreads();
    for (int off = 1; off < 256; off <<= 1) {
        int tmp[NS];
        #pragma unroll
        for (int e = 0; e < NS; e++) tmp[e] = (t >= off) ? sc_[t - off][e] : 0;
        __syncthreads();
        #pragma unroll
        for (int e = 0; e < NS; e++) sc_[t][e] += tmp[e];
        __syncthreads();
    }
    if (t == 0) {
        int run = 0;
        for (int e = 0; e < NS; e++) {
            st_[e] = run; start[e] = run; cnt[e] = sc_[255][e]; run += sc_[255][e];
        }
    }
    __syncthreads();
    #pragma unroll
    for (int r = 0; r < 8; r++) {
        const int e = myspec[r];
        int rank = 0;
        #pragma unroll
        for (int r2 = 0; r2 < r; r2++) rank += (myspec[r2] == e) ? 1 : 0;
        const int pos = st_[e] + (sc_[t][e] - own_[t][e]) + rank;
        list[pos] = t * 8 + r;
    }
}

// ---------------- main: per-(e,c) table build + contraction (2 b / thread) ---
__global__ __launch_bounds__(128, 4) void main_kernel(
    const float* __restrict__ x_in,
    const float* __restrict__ U1, const float* __restrict__ U2, const float* __restrict__ U3,
    const float* __restrict__ W1, const float* __restrict__ W2, const float* __restrict__ W3,
    const int* __restrict__ cnt, const int* __restrict__ start, const int* __restrict__ list,
    float* __restrict__ inter)
{
    const int c = blockIdx.x;
    const int e = blockIdx.y;
    const int count = cnt[e];
    const int sbase = start[e];

    __shared__ float stab[219 * 12];   // 10512 B
    __shared__ float w3s[3][8];
    __shared__ float w2s[3][3];
    __shared__ float w1s[3];

    const int t = threadIdx.x;
    if (t < 24)      { int l = t / 8, p = t % 8; w3s[l][p] = W3[((l * NS + e) * 8 + p) * NC + c]; }
    else if (t < 33) { int q = t - 24; int l = q / 3, p = q % 3; w2s[l][p] = W2[((l * NS + e) * 3 + p) * NC + c]; }
    else if (t < 36) { int l = t - 33; w1s[l] = W1[(l * NS + e) * NC + c]; }
    __syncthreads();

    // ---- build symmetrized table: 1971 (row, mm) slots ----
    for (int n = t; n < 219 * 9; n += 128) {
        const int row = n / 9;
        const int mm = n - row * 9;
        int l, lm;
        if (mm == 0) { l = 0; lm = 0; } else if (mm < 4) { l = 1; lm = 4 + mm; } else { l = 2; lm = 6 + mm; }
        float val = 0.f;
        if (row < 165) {
            const int ia = TT.ti[row], jb = TT.tj[row], kc = TT.tk[row];
            const bool eab = (ia == jb), ebc = (jb == kc);
            const float* w = &w3s[l][0];
            float s = 0.f;
            auto addp = [&](int pi, int pj, int pk) {
                const float4* q = (const float4*)(U3 + ((size_t)lm * 729 + pi * 81 + pj * 9 + pk) * 8);
                const float4 A = q[0], Bv = q[1];
                float av = A.x * w[0];
                av = fmaf(A.y,  w[1], av);
                av = fmaf(A.z,  w[2], av);
                av = fmaf(A.w,  w[3], av);
                av = fmaf(Bv.x, w[4], av);
                av = fmaf(Bv.y, w[5], av);
                av = fmaf(Bv.z, w[6], av);
                av = fmaf(Bv.w, w[7], av);
                s += av;
            };
            addp(ia, jb, kc);
            if (!ebc)          addp(ia, kc, jb);
            if (!eab)          addp(jb, ia, kc);
            if (!eab)          addp(jb, kc, ia);
            if (!ebc)          addp(kc, ia, jb);
            if (!(eab || ebc)) addp(kc, jb, ia);
            val = s;
        } else if (row < 210) {
            const int n2 = row - 165;
            const int j = PT.pj[n2], k = PT.pk[n2];
            const float* u2a = U2 + ((size_t)lm * 81 + j * 9 + k) * 3;
            float av = fmaf(u2a[0], w2s[l][0], fmaf(u2a[1], w2s[l][1], u2a[2] * w2s[l][2]));
            if (j != k) {
                const float* u2b = U2 + ((size_t)lm * 81 + k * 9 + j) * 3;
                av = fmaf(u2b[0], w2s[l][0], fmaf(u2b[1], w2s[l][1], fmaf(u2b[2], w2s[l][2], av)));
            }
            val = av;
        } else {
            val = U1[lm * 9 + (row - 210)] * w1s[l];
        }
        stab[row * 12 + mm] = val;
    }
    __syncthreads();

    // ---- contraction: 2 b's per thread, 9+9 independent acc chains ----
    #pragma unroll 1
    for (int base = 0; base < count; base += 256) {
        const int ia0 = base + t;
        const int ia1 = base + t + 128;
        const bool act0 = ia0 < count;
        const bool act1 = ia1 < count;
        const int slot0 = sbase + (act0 ? ia0 : 0);
        const int slot1 = sbase + (act1 ? ia1 : 0);
        const int b0 = list[slot0];
        const int b1 = list[slot1];

        float xa[9], xb[9];
        const float* xpa = x_in + ((size_t)b0 * NC + c) * 9;
        const float* xpb = x_in + ((size_t)b1 * NC + c) * 9;
        #pragma unroll
        for (int k = 0; k < 9; k++) { xa[k] = xpa[k]; xb[k] = xpb[k]; }

        float acca[9] = {0,0,0,0,0,0,0,0,0};
        float accb[9] = {0,0,0,0,0,0,0,0,0};

        #define ROWFMA2(ROWIDX, MOA, MOB)                                      \
            {                                                                  \
                const float* r_ = stab + (ROWIDX) * 12;                        \
                const float4 r0_ = *(const float4*)r_;                         \
                const float4 r1_ = *(const float4*)(r_ + 4);                   \
                const float  r8_ = r_[8];                                      \
                const float  ma_ = (MOA);                                      \
                const float  mb_ = (MOB);                                      \
                acca[0] = fmaf(r0_.x, ma_, acca[0]);                           \
                acca[1] = fmaf(r0_.y, ma_, acca[1]);                           \
                acca[2] = fmaf(r0_.z, ma_, acca[2]);                           \
                acca[3] = fmaf(r0_.w, ma_, acca[3]);                           \
                acca[4] = fmaf(r1_.x, ma_, acca[4]);                           \
                acca[5] = fmaf(r1_.y, ma_, acca[5]);                           \
                acca[6] = fmaf(r1_.z, ma_, acca[6]);                           \
                acca[7] = fmaf(r1_.w, ma_, acca[7]);                           \
                acca[8] = fmaf(r8_,  ma_, acca[8]);                            \
                accb[0] = fmaf(r0_.x, mb_, accb[0]);                           \
                accb[1] = fmaf(r0_.y, mb_, accb[1]);                           \
                accb[2] = fmaf(r0_.z, mb_, accb[2]);                           \
                accb[3] = fmaf(r0_.w, mb_, accb[3]);                           \
                accb[4] = fmaf(r1_.x, mb_, accb[4]);                           \
                accb[5] = fmaf(r1_.y, mb_, accb[5]);                           \
                accb[6] = fmaf(r1_.z, mb_, accb[6]);                           \
                accb[7] = fmaf(r1_.w, mb_, accb[7]);                           \
                accb[8] = fmaf(r8_,  mb_, accb[8]);                            \
            }

        // cubic monomials
        #pragma unroll
        for (int i = 0; i < 9; i++) {
            #pragma unroll
            for (int j = i; j < 9; j++) {
                const float xija = xa[i] * xa[j];
                const float xijb = xb[i] * xb[j];
                #pragma unroll
                for (int k = j; k < 9; k++) {
                    ROWFMA2(tidx(i, j, k), xija * xa[k], xijb * xb[k]);
                }
                __builtin_amdgcn_sched_barrier(0);
            }
        }
        // quadratic monomials
        #pragma unroll
        for (int j = 0; j < 9; j++) {
            #pragma unroll
            for (int k = j; k < 9; k++) {
                ROWFMA2(165 + pidx(j, k), xa[j] * xa[k], xb[j] * xb[k]);
            }
            __builtin_amdgcn_sched_barrier(0);
        }
        // linear monomials
        #pragma unroll
        for (int i = 0; i < 9; i++) {
            ROWFMA2(210 + i, xa[i], xb[i]);
        }
        __builtin_amdgcn_sched_barrier(0);
        #undef ROWFMA2

        if (act0) {
            float* op = inter + ((size_t)c * NB + slot0) * 12;
            *(float4*)(op)     = make_float4(acca[0], acca[1], acca[2], acca[3]);
            *(float4*)(op + 4) = make_float4(acca[4], acca[5], acca[6], acca[7]);
            *(float4*)(op + 8) = make_float4(acca[8], 0.f, 0.f, 0.f);
        }
        if (act1) {
            float* op = inter + ((size_t)c * NB + slot1) * 12;
            *(float4*)(op)     = make_float4(accb[0], accb[1], accb[2], accb[3]);
            *(float4*)(op + 4) = make_float4(accb[4], accb[5], accb[6], accb[7]);
            *(float4*)(op + 8) = make_float4(accb[8], 0.f, 0.f, 0.f);
        }
    }
}

// ---------------- final: y[b,dd,m] = sum_c inter[c,slot,mm]*Wlin[l,c,dd]/sqrt(C) + sc
__global__ __launch_bounds__(256) void final_kernel(
    const float* __restrict__ inter, const float* __restrict__ Wlin,
    const float* __restrict__ sc, const int* __restrict__ list,
    float* __restrict__ out)
{
    __shared__ float sInter[4 * NC * 12];   // 24 KB, layout [s][c][12]
    const int t = threadIdx.x;
    const int s0 = blockIdx.x * 4;
    #pragma unroll
    for (int q = 0; q < 6; q++) {
        const int flat = t + q * 256;        // [0, 1536)
        const int q3 = flat % 3;
        const int cs = flat / 3;             // [0, 512)
        const int cc = cs >> 2, s = cs & 3;
        const float4 v = *(const float4*)(inter + ((size_t)cc * NB + s0 + s) * 12 + q3 * 4);
        *(float4*)(&sInter[(s * NC + cc) * 12 + q3 * 4]) = v;
    }
    __syncthreads();

    const int dd = t & 127;
    const int bh = t >> 7;
    float acc[2][9];
    #pragma unroll
    for (int u = 0; u < 2; u++)
        #pragma unroll
        for (int mm = 0; mm < 9; mm++) acc[u][mm] = 0.f;

    const float* wp = Wlin + dd;
    for (int cc = 0; cc < NC; cc++) {
        const float wl0 = wp[(0 * NC + cc) * NC];
        const float wl1 = wp[(1 * NC + cc) * NC];
        const float wl2 = wp[(2 * NC + cc) * NC];
        #pragma unroll
        for (int u = 0; u < 2; u++) {
            const float* ip = sInter + ((bh + u * 2) * NC + cc) * 12;
            const float4 i0 = *(const float4*)ip;
            const float4 i1 = *(const float4*)(ip + 4);
            const float  i8 = ip[8];
            acc[u][0] = fmaf(i0.x, wl0, acc[u][0]);
            acc[u][1] = fmaf(i0.y, wl1, acc[u][1]);
            acc[u][2] = fmaf(i0.z, wl1, acc[u][2]);
            acc[u][3] = fmaf(i0.w, wl1, acc[u][3]);
            acc[u][4] = fmaf(i1.x, wl2, acc[u][4]);
            acc[u][5] = fmaf(i1.y, wl2, acc[u][5]);
            acc[u][6] = fmaf(i1.z, wl2, acc[u][6]);
            acc[u][7] = fmaf(i1.w, wl2, acc[u][7]);
            acc[u][8] = fmaf(i8,   wl2, acc[u][8]);
        }
    }

    const float inv = 0.08838834764831845f;   // 1/sqrt(128)
    #pragma unroll
    for (int u = 0; u < 2; u++) {
        const int s = s0 + bh + u * 2;
        const int b = list[s];
        float* orow = out + (size_t)b * 1152;
        const float* scrow = sc + (size_t)b * 1152;
        orow[dd] = fmaf(acc[u][0], inv, scrow[dd]);
        #pragma unroll
        for (int m = 0; m < 3; m++)
            orow[128 + dd * 3 + m] = fmaf(acc[u][1 + m], inv, scrow[128 + dd * 3 + m]);
        #pragma unroll
        for (int m = 0; m < 5; m++)
            orow[512 + dd * 5 + m] = fmaf(acc[u][4 + m], inv, scrow[512 + dd * 5 + m]);
    }
}

extern "C" void kernel_launch(void* const* d_in, const int* in_sizes, int n_in,
                              void* d_out, int out_size, void* d_ws, size_t ws_size,
                              hipStream_t stream) {
    const float* node_feats = (const float*)d_in[0];
    const float* node_attrs = (const float*)d_in[1];
    const float* sc   = (const float*)d_in[2];
    const float* U1   = (const float*)d_in[3];
    const float* U2   = (const float*)d_in[4];
    const float* U3   = (const float*)d_in[5];
    const float* W1   = (const float*)d_in[6];
    const float* W2   = (const float*)d_in[7];
    const float* W3   = (const float*)d_in[8];
    const float* Wlin = (const float*)d_in[9];
    float* out = (float*)d_out;

    char* ws = (char*)d_ws;
    int* cnt   = (int*)(ws + 0);
    int* start = (int*)(ws + 64);
    int* list  = (int*)(ws + 128);
    float* inter = (float*)(ws + 16384);   // NC*NB*12 floats = 12.58 MB

    hipLaunchKernelGGL(prep_kernel, dim3(1), dim3(256), 0, stream,
                       node_attrs, cnt, start, list);
    hipLaunchKernelGGL(main_kernel, dim3(NC, NS), dim3(128), 0, stream,
                       node_feats, U1, U2, U3, W1, W2, W3, cnt, start, list, inter);
    hipLaunchKernelGGL(final_kernel, dim3(NB / 4), dim3(256), 0, stream,
                       inter, Wlin, sc, list, out);
}

// Round 5
// 95.710 us; speedup vs baseline: 11.9689x; 11.9689x over previous
//
#include <hip/hip_runtime.h>

// EquivariantProductBasisBlock (MACE symmetric contraction), fp32.
// B=2048, C=128, S=10, DIN=9, DOUTS=(1,3,5), PATHS=(1,3,8).
//
// R5: R1's proven loop structure (dynamic mm outer, single acc tree, float4
// LDS rows consumed immediately) + symmetrized [mm]-major padded table.
// Per mm (stride 660 floats):
//   S3: 45 pair slots (i<=j), slot pidx(i,j)*12, value for k at (k-j)
//   S2: 9 j slots at 540+j*12, value for k at (k-j)
//   S1: 9 values at 648+i
// sym_kernel precomputes c-independent perm-symmetrized U3sym/U2sym.
//
// mm -> (l,m): 0 -> (0,0); 1..3 -> (1,mm-1); 4..8 -> (2,mm-4); lm = l*5+m.

#define NB 2048
#define NC 128
#define NS 10

__host__ __device__ constexpr int pidx(int j, int k) {  // (j<=k) -> [0,45)
    return 9 * j - j * (j - 1) / 2 + (k - j);
}

struct TripTab {     // i<=j<=k lexicographic
    int ti[165], tj[165], tk[165];
    constexpr TripTab() : ti{}, tj{}, tk{} {
        int n = 0;
        for (int i = 0; i < 9; i++)
            for (int j = i; j < 9; j++)
                for (int k = j; k < 9; k++) { ti[n] = i; tj[n] = j; tk[n] = k; n++; }
    }
};
static constexpr TripTab TT{};

struct PairTab {     // j<=k in pidx order
    int pj[45], pk[45];
    constexpr PairTab() : pj{}, pk{} {
        int n = 0;
        for (int j = 0; j < 9; j++)
            for (int k = j; k < 9; k++) { pj[n] = j; pk[n] = k; n++; }
    }
};
static constexpr PairTab PT{};

// ---------------- prep: deterministic counting sort of b by species ----------
__global__ __launch_bounds__(256) void prep_kernel(const float* __restrict__ attrs,
                                                   int* __restrict__ cnt,
                                                   int* __restrict__ start,
                                                   int* __restrict__ list)
{
    __shared__ int sc_[256][NS];
    __shared__ int own_[256][NS];
    __shared__ int st_[NS];
    const int t = threadIdx.x;
    int myspec[8];
    #pragma unroll
    for (int e = 0; e < NS; e++) own_[t][e] = 0;
    #pragma unroll
    for (int r = 0; r < 8; r++) {
        const int b = t * 8 + r;
        const float* row = attrs + b * NS;
        int e = 0;
        #pragma unroll
        for (int s = 1; s < NS; s++) e = (row[s] > 0.5f) ? s : e;
        myspec[r] = e;
        own_[t][e] += 1;
    }
    #pragma unroll
    for (int e = 0; e < NS; e++) sc_[t][e] = own_[t][e];
    __syncthreads();
    for (int off = 1; off < 256; off <<= 1) {
        int tmp[NS];
        #pragma unroll
        for (int e = 0; e < NS; e++) tmp[e] = (t >= off) ? sc_[t - off][e] : 0;
        __syncthreads();
        #pragma unroll
        for (int e = 0; e < NS; e++) sc_[t][e] += tmp[e];
        __syncthreads();
    }
    if (t == 0) {
        int run = 0;
        for (int e = 0; e < NS; e++) {
            st_[e] = run; start[e] = run; cnt[e] = sc_[255][e]; run += sc_[255][e];
        }
    }
    __syncthreads();
    #pragma unroll
    for (int r = 0; r < 8; r++) {
        const int e = myspec[r];
        int rank = 0;
        #pragma unroll
        for (int r2 = 0; r2 < r; r2++) rank += (myspec[r2] == e) ? 1 : 0;
        const int pos = st_[e] + (sc_[t][e] - own_[t][e]) + rank;
        list[pos] = t * 8 + r;
    }
}

// ---------------- sym: perm-symmetrize U3, U2 (c-independent) ----------------
__global__ __launch_bounds__(256) void sym_kernel(const float* __restrict__ U2,
                                                  const float* __restrict__ U3,
                                                  float* __restrict__ U3sym,
                                                  float* __restrict__ U2sym)
{
    const int lm = blockIdx.x;     // 0..14
    const int t = threadIdx.x;
    if (t < 165) {
        const int i = TT.ti[t], j = TT.tj[t], k = TT.tk[t];
        const bool eab = (i == j), ebc = (j == k);
        float s[8] = {0, 0, 0, 0, 0, 0, 0, 0};
        auto addp = [&](int a, int b, int c) {
            const float* q = U3 + (((size_t)lm * 729) + a * 81 + b * 9 + c) * 8;
            #pragma unroll
            for (int p = 0; p < 8; p++) s[p] += q[p];
        };
        addp(i, j, k);
        if (!ebc)          addp(i, k, j);
        if (!eab)          addp(j, i, k);
        if (!eab)          addp(j, k, i);
        if (!ebc)          addp(k, i, j);
        if (!(eab || ebc)) addp(k, j, i);
        float* o = U3sym + ((size_t)lm * 165 + t) * 8;
        #pragma unroll
        for (int p = 0; p < 8; p++) o[p] = s[p];
    } else if (t < 210) {
        const int pp = t - 165;
        const int j = PT.pj[pp], k = PT.pk[pp];
        const float* a = U2 + ((size_t)lm * 81 + j * 9 + k) * 3;
        float v0 = a[0], v1 = a[1], v2 = a[2];
        if (j != k) {
            const float* b2 = U2 + ((size_t)lm * 81 + k * 9 + j) * 3;
            v0 += b2[0]; v1 += b2[1]; v2 += b2[2];
        }
        float* o = U2sym + ((size_t)lm * 45 + pp) * 3;
        o[0] = v0; o[1] = v1; o[2] = v2;
    }
}

// ---------------- main: per-(e,c) table build + per-b contraction ------------
__global__ __launch_bounds__(256) void main_kernel(
    const float* __restrict__ x_in,
    const float* __restrict__ U1,
    const float* __restrict__ U3sym, const float* __restrict__ U2sym,
    const float* __restrict__ W1, const float* __restrict__ W2, const float* __restrict__ W3,
    const int* __restrict__ cnt, const int* __restrict__ start, const int* __restrict__ list,
    float* __restrict__ inter)
{
    const int c = blockIdx.x;
    const int e = blockIdx.y;
    const int count = cnt[e];
    const int sbase = start[e];

    __shared__ __align__(16) float stab[9 * 660];   // 23760 B
    __shared__ float w3s[3][8];
    __shared__ float w2s[3][3];
    __shared__ float w1s[3];

    const int t = threadIdx.x;
    if (t < 24)      { int l = t / 8, p = t % 8; w3s[l][p] = W3[((l * NS + e) * 8 + p) * NC + c]; }
    else if (t < 33) { int q = t - 24; int l = q / 3, p = q % 3; w2s[l][p] = W2[((l * NS + e) * 3 + p) * NC + c]; }
    else if (t < 36) { int l = t - 33; w1s[l] = W1[(l * NS + e) * NC + c]; }
    __syncthreads();

    // ---- build table: 495 slots of 12 floats ----
    {
        const int TB[9] = {0, 45, 81, 109, 130, 145, 155, 161, 164};
        for (int n = t; n < 495; n += 256) {
            const int mm = n / 55;
            const int s = n - mm * 55;
            int l, lm;
            if (mm == 0) { l = 0; lm = 0; } else if (mm < 4) { l = 1; lm = 4 + mm; } else { l = 2; lm = 6 + mm; }
            float* tb = stab + mm * 660;
            if (s < 45) {
                const int i = PT.pj[s], j = PT.pk[s];
                const int jj = j - i;
                const int t0 = TB[i] + (9 - i) * jj - jj * (jj - 1) / 2;
                for (int u = 0; u < 12; u++) {
                    float val = 0.f;
                    if (u < 9 - j) {
                        const float* a = U3sym + ((size_t)lm * 165 + t0 + u) * 8;
                        const float4 A = *(const float4*)a;
                        const float4 Bv = *(const float4*)(a + 4);
                        val = A.x * w3s[l][0];
                        val = fmaf(A.y,  w3s[l][1], val);
                        val = fmaf(A.z,  w3s[l][2], val);
                        val = fmaf(A.w,  w3s[l][3], val);
                        val = fmaf(Bv.x, w3s[l][4], val);
                        val = fmaf(Bv.y, w3s[l][5], val);
                        val = fmaf(Bv.z, w3s[l][6], val);
                        val = fmaf(Bv.w, w3s[l][7], val);
                    }
                    tb[s * 12 + u] = val;
                }
            } else if (s < 54) {
                const int j = s - 45;
                for (int u = 0; u < 12; u++) {
                    float val = 0.f;
                    if (u < 9 - j) {
                        const int pp = pidx(j, j + u);
                        const float* a = U2sym + ((size_t)lm * 45 + pp) * 3;
                        val = fmaf(a[0], w2s[l][0], fmaf(a[1], w2s[l][1], a[2] * w2s[l][2]));
                    }
                    tb[540 + j * 12 + u] = val;
                }
            } else {
                for (int u = 0; u < 12; u++) {
                    float val = (u < 9) ? U1[lm * 9 + u] * w1s[l] : 0.f;
                    tb[648 + u] = val;
                }
            }
        }
    }
    __syncthreads();

    // ---- contraction: one (b,c) per thread, R1-style single acc tree ----
    #pragma unroll 1
    for (int idx = t; idx < count; idx += 256) {
        const int slot = sbase + idx;
        const int b = list[slot];
        const float* xp = x_in + ((size_t)b * NC + c) * 9;
        float x[9];
        #pragma unroll
        for (int k = 0; k < 9; k++) x[k] = xp[k];

        float* op = inter + ((size_t)c * NB + slot) * 12;

        #pragma unroll 1
        for (int mm = 0; mm < 9; mm++) {
            const float* bp = stab + mm * 660;
            float acc = 0.f;
            // S3: sum_i x_i sum_{j>=i} x_j sum_{k>=j} S3*x_k
            #pragma unroll
            for (int i = 0; i < 9; i++) {
                float acci = 0.f;
                #pragma unroll
                for (int j = i; j < 9; j++) {
                    const float* r = bp + pidx(i, j) * 12;
                    const int L = 9 - j;
                    const float4 q0 = *(const float4*)r;
                    float inner = q0.x * x[j];
                    if (L > 1) inner = fmaf(q0.y, x[j + 1], inner);
                    if (L > 2) inner = fmaf(q0.z, x[j + 2], inner);
                    if (L > 3) inner = fmaf(q0.w, x[j + 3], inner);
                    if (L > 4) {
                        const float4 q1 = *(const float4*)(r + 4);
                        inner = fmaf(q1.x, x[j + 4], inner);
                        if (L > 5) inner = fmaf(q1.y, x[j + 5], inner);
                        if (L > 6) inner = fmaf(q1.z, x[j + 6], inner);
                        if (L > 7) inner = fmaf(q1.w, x[j + 7], inner);
                        if (L > 8) {
                            const float4 q2 = *(const float4*)(r + 8);
                            inner = fmaf(q2.x, x[j + 8], inner);
                        }
                    }
                    acci = fmaf(x[j], inner, acci);
                }
                acc = fmaf(x[i], acci, acc);
            }
            // S2: sum_j x_j sum_{k>=j} S2*x_k
            #pragma unroll
            for (int j = 0; j < 9; j++) {
                const float* r = bp + 540 + j * 12;
                const int L = 9 - j;
                const float4 q0 = *(const float4*)r;
                float inner = q0.x * x[j];
                if (L > 1) inner = fmaf(q0.y, x[j + 1], inner);
                if (L > 2) inner = fmaf(q0.z, x[j + 2], inner);
                if (L > 3) inner = fmaf(q0.w, x[j + 3], inner);
                if (L > 4) {
                    const float4 q1 = *(const float4*)(r + 4);
                    inner = fmaf(q1.x, x[j + 4], inner);
                    if (L > 5) inner = fmaf(q1.y, x[j + 5], inner);
                    if (L > 6) inner = fmaf(q1.z, x[j + 6], inner);
                    if (L > 7) inner = fmaf(q1.w, x[j + 7], inner);
                    if (L > 8) {
                        const float4 q2 = *(const float4*)(r + 8);
                        inner = fmaf(q2.x, x[j + 8], inner);
                    }
                }
                acc = fmaf(x[j], inner, acc);
            }
            // S1
            {
                const float* r = bp + 648;
                const float4 q0 = *(const float4*)r;
                const float4 q1 = *(const float4*)(r + 4);
                float inner = q0.x * x[0];
                inner = fmaf(q0.y, x[1], inner);
                inner = fmaf(q0.z, x[2], inner);
                inner = fmaf(q0.w, x[3], inner);
                inner = fmaf(q1.x, x[4], inner);
                inner = fmaf(q1.y, x[5], inner);
                inner = fmaf(q1.z, x[6], inner);
                inner = fmaf(q1.w, x[7], inner);
                inner = fmaf(r[8], x[8], inner);
                acc += inner;
            }
            op[mm] = acc;
        }
    }
}

// ---------------- final: y[b,dd,m] = sum_c inter[c,slot,mm]*Wlin[l,c,dd]/sqrt(C) + sc
__global__ __launch_bounds__(256) void final_kernel(
    const float* __restrict__ inter, const float* __restrict__ Wlin,
    const float* __restrict__ sc, const int* __restrict__ list,
    float* __restrict__ out)
{
    __shared__ float sInter[4 * NC * 12];   // 24 KB, layout [s][c][12]
    const int t = threadIdx.x;
    const int s0 = blockIdx.x * 4;
    #pragma unroll
    for (int q = 0; q < 6; q++) {
        const int flat = t + q * 256;        // [0, 1536)
        const int q3 = flat % 3;
        const int cs = flat / 3;             // [0, 512)
        const int cc = cs >> 2, s = cs & 3;
        const float4 v = *(const float4*)(inter + ((size_t)cc * NB + s0 + s) * 12 + q3 * 4);
        *(float4*)(&sInter[(s * NC + cc) * 12 + q3 * 4]) = v;
    }
    __syncthreads();

    const int dd = t & 127;
    const int bh = t >> 7;
    float acc[2][9];
    #pragma unroll
    for (int u = 0; u < 2; u++)
        #pragma unroll
        for (int mm = 0; mm < 9; mm++) acc[u][mm] = 0.f;

    const float* wp = Wlin + dd;
    for (int cc = 0; cc < NC; cc++) {
        const float wl0 = wp[(0 * NC + cc) * NC];
        const float wl1 = wp[(1 * NC + cc) * NC];
        const float wl2 = wp[(2 * NC + cc) * NC];
        #pragma unroll
        for (int u = 0; u < 2; u++) {
            const float* ip = sInter + ((bh + u * 2) * NC + cc) * 12;
            const float4 i0 = *(const float4*)ip;
            const float4 i1 = *(const float4*)(ip + 4);
            const float  i8 = ip[8];
            acc[u][0] = fmaf(i0.x, wl0, acc[u][0]);
            acc[u][1] = fmaf(i0.y, wl1, acc[u][1]);
            acc[u][2] = fmaf(i0.z, wl1, acc[u][2]);
            acc[u][3] = fmaf(i0.w, wl1, acc[u][3]);
            acc[u][4] = fmaf(i1.x, wl2, acc[u][4]);
            acc[u][5] = fmaf(i1.y, wl2, acc[u][5]);
            acc[u][6] = fmaf(i1.z, wl2, acc[u][6]);
            acc[u][7] = fmaf(i1.w, wl2, acc[u][7]);
            acc[u][8] = fmaf(i8,   wl2, acc[u][8]);
        }
    }

    const float inv = 0.08838834764831845f;   // 1/sqrt(128)
    #pragma unroll
    for (int u = 0; u < 2; u++) {
        const int s = s0 + bh + u * 2;
        const int b = list[s];
        float* orow = out + (size_t)b * 1152;
        const float* scrow = sc + (size_t)b * 1152;
        orow[dd] = fmaf(acc[u][0], inv, scrow[dd]);
        #pragma unroll
        for (int m = 0; m < 3; m++)
            orow[128 + dd * 3 + m] = fmaf(acc[u][1 + m], inv, scrow[128 + dd * 3 + m]);
        #pragma unroll
        for (int m = 0; m < 5; m++)
            orow[512 + dd * 5 + m] = fmaf(acc[u][4 + m], inv, scrow[512 + dd * 5 + m]);
    }
}

extern "C" void kernel_launch(void* const* d_in, const int* in_sizes, int n_in,
                              void* d_out, int out_size, void* d_ws, size_t ws_size,
                              hipStream_t stream) {
    const float* node_feats = (const float*)d_in[0];
    const float* node_attrs = (const float*)d_in[1];
    const float* sc   = (const float*)d_in[2];
    const float* U1   = (const float*)d_in[3];
    const float* U2   = (const float*)d_in[4];
    const float* U3   = (const float*)d_in[5];
    const float* W1   = (const float*)d_in[6];
    const float* W2   = (const float*)d_in[7];
    const float* W3   = (const float*)d_in[8];
    const float* Wlin = (const float*)d_in[9];
    float* out = (float*)d_out;

    char* ws = (char*)d_ws;
    int* cnt     = (int*)(ws + 0);
    int* start   = (int*)(ws + 64);
    int* list    = (int*)(ws + 128);              // 8 KB
    float* U3sym = (float*)(ws + 16384);          // 79200 B
    float* U2sym = (float*)(ws + 98304);          // 8100 B
    float* inter = (float*)(ws + 131072);         // NC*NB*12 floats = 12.58 MB

    hipLaunchKernelGGL(prep_kernel, dim3(1), dim3(256), 0, stream,
                       node_attrs, cnt, start, list);
    hipLaunchKernelGGL(sym_kernel, dim3(15), dim3(256), 0, stream,
                       U2, U3, U3sym, U2sym);
    hipLaunchKernelGGL(main_kernel, dim3(NC, NS), dim3(256), 0, stream,
                       node_feats, U1, U3sym, U2sym, W1, W2, W3, cnt, start, list, inter);
    hipLaunchKernelGGL(final_kernel, dim3(NB / 4), dim3(256), 0, stream,
                       inter, Wlin, sc, list, out);
}